// Round 3
// baseline (683.373 us; speedup 1.0000x reference)
//
#include <hip/hip_runtime.h>

#define B_CNT 4
#define N_CNT 10000
#define E_CNT 100000
#define AGG_PAIRS 24
#define AGG_BLOCKS ((B_CNT * N_CNT + AGG_PAIRS - 1) / AGG_PAIRS)  // 1667

typedef __attribute__((ext_vector_type(8))) short s16x8;
typedef __attribute__((ext_vector_type(4))) float f32x4;

__device__ __forceinline__ float b2f(unsigned short u) {
  union { unsigned int i; float f; } v; v.i = ((unsigned int)u) << 16; return v.f;
}
__device__ __forceinline__ unsigned short f2b(float f) {
  union { float f; unsigned int i; } v; v.f = f;
  unsigned int b = v.i;
  b += 0x7FFFu + ((b >> 16) & 1u);   // round-to-nearest-even
  return (unsigned short)(b >> 16);
}
__device__ __forceinline__ short f2bs(float f) { return (short)f2b(f); }

// ---------------------------------------------------------------------------
// K_pre: fused preprocessing.
//   blocks [0,40)   : spectral transform x(4,N,16) -> xnew fp32
//   blocks [40,72)  : pack W1/W2 fp32 -> bf16 MFMA B-fragment order
//   blocks [72,463) : per-node in-degree histogram
// ---------------------------------------------------------------------------
__global__ void k_pre(const float* __restrict__ x,
                      const float* __restrict__ tcwr,
                      const float* __restrict__ tcwi,
                      const float* __restrict__ w1,
                      const float* __restrict__ w2,
                      const int* __restrict__ eidx,
                      float* __restrict__ xnew,
                      unsigned short* __restrict__ pw1,
                      unsigned short* __restrict__ pw2,
                      int* __restrict__ cnt) {
  __shared__ float Wr[256], Wi[256];
  const int bid = blockIdx.x;
  const int t = threadIdx.x;

  if (bid < 40) {
    // ---- spectral transform (closed-form rfft/irfft over batch axis, n=4) ----
    Wr[t] = tcwr[t * 2] + tcwr[t * 2 + 1];   // sum over MODES
    Wi[t] = tcwi[t * 2] + tcwi[t * 2 + 1];
    __syncthreads();
    const int n = bid * 256 + t;
    if (n >= N_CNT) return;
    float xt[4][16];
    for (int tt = 0; tt < 4; ++tt) {
      const float* xp = x + ((size_t)tt * N_CNT + n) * 16;
#pragma unroll
      for (int i0 = 0; i0 < 16; i0 += 4) {
        const float4 v = *(const float4*)(xp + i0);
        xt[tt][i0 + 0] = v.x; xt[tt][i0 + 1] = v.y;
        xt[tt][i0 + 2] = v.z; xt[tt][i0 + 3] = v.w;
      }
    }
    float s[16], a[16], bb[16];
#pragma unroll
    for (int i = 0; i < 16; ++i) {
      s[i]  = xt[0][i] + xt[1][i] + xt[2][i] + xt[3][i];
      a[i]  = xt[0][i] - xt[2][i];
      bb[i] = xt[1][i] - xt[3][i];
    }
    for (int o = 0; o < 16; ++o) {
      float r0 = 0.f, p = 0.f, qq = 0.f;
#pragma unroll
      for (int i = 0; i < 16; ++i) {
        const float wr = Wr[i * 16 + o], wi = Wi[i * 16 + o];
        r0 += s[i] * wr;
        p  += a[i] * wr + bb[i] * wi;
        qq += a[i] * wi - bb[i] * wr;
      }
      xnew[((size_t)0 * N_CNT + n) * 16 + o] = 0.25f * (r0 + 2.f * p);
      xnew[((size_t)1 * N_CNT + n) * 16 + o] = 0.25f * (r0 - 2.f * qq);
      xnew[((size_t)2 * N_CNT + n) * 16 + o] = 0.25f * (r0 - 2.f * p);
      xnew[((size_t)3 * N_CNT + n) * 16 + o] = 0.25f * (r0 + 2.f * qq);
    }
  } else if (bid < 72) {
    // ---- weight pack: tile(nt,kk): lane l -> W[kk*32+(l>>4)*8+j][nt*16+(l&15)]
    const int tg = (bid - 40) * 256 + t;  // 0..8191
    const int tile = tg >> 6, l = tg & 63, q = l >> 4, lm = l & 15;
    if (tile < 32) {
      const int nt = tile >> 2, kk = tile & 3;
      const int n = nt * 16 + lm;
      unsigned short* dst = pw1 + ((size_t)tile * 64 + l) * 8;
#pragma unroll
      for (int j = 0; j < 8; ++j) dst[j] = f2b(w1[(kk * 32 + q * 8 + j) * 128 + n]);
    } else {
      const int t2 = tile - 32;  // 0..95
      const int nt = t2 >> 2, kk = t2 & 3;
      const int n = nt * 16 + lm;
      unsigned short* dst = pw2 + ((size_t)t2 * 64 + l) * 8;
#pragma unroll
      for (int j = 0; j < 8; ++j) dst[j] = f2b(w2[(kk * 32 + q * 8 + j) * 384 + n]);
    }
  } else {
    const int e = (bid - 72) * 256 + t;
    if (e < E_CNT) atomicAdd(&cnt[eidx[E_CNT + e]], 1);
  }
}

// ---------------------------------------------------------------------------
// K_scan: exclusive prefix sum of cnt[10000] -> rowptr[10001]. One block.
// ---------------------------------------------------------------------------
__global__ void k_scan(const int* __restrict__ cnt, int* __restrict__ rowptr) {
  __shared__ int part[256];
  const int t = threadIdx.x;
  const int base = t * 40;
  int s = 0;
  for (int k = 0; k < 40; ++k) {
    const int idx = base + k;
    s += (idx < N_CNT) ? cnt[idx] : 0;
  }
  part[t] = s;
  __syncthreads();
  for (int off = 1; off < 256; off <<= 1) {
    const int v = (t >= off) ? part[t - off] : 0;
    __syncthreads();
    part[t] += v;
    __syncthreads();
  }
  int run = (t > 0) ? part[t - 1] : 0;
  for (int k = 0; k < 40; ++k) {
    const int idx = base + k;
    if (idx < N_CNT) { rowptr[idx] = run; run += cnt[idx]; }
  }
  if (t == 255) rowptr[N_CNT] = part[255];
}

// ---------------------------------------------------------------------------
// K_fill: scatter edge ids into dst-sorted order. perm[sorted_pos] = edge id.
// ---------------------------------------------------------------------------
__global__ void k_fill(const int* __restrict__ eidx, const int* __restrict__ rowptr,
                       int* __restrict__ cursor, int* __restrict__ perm) {
  const int e = blockIdx.x * 256 + threadIdx.x;
  if (e < E_CNT) {
    const int d = eidx[E_CNT + e];
    const int pos = atomicAdd(&cursor[d], 1);
    perm[rowptr[d] + pos] = e;
  }
}

// ---------------------------------------------------------------------------
// K_edge: per block: 32 dst-sorted edges, one batch.
//   GEMM1: H(32x128) = relu(EA @ W1 + b1)      (MFMA, A row-gather via perm)
//   GEMM2: EW(32x384) = H @ W2 + b2            (MFMA, A from LDS)
//   messages -> contiguous bf16 store into msg[b][sorted_pos][40] (NO atomics)
// ---------------------------------------------------------------------------
__global__ __launch_bounds__(256) void k_edge(
    const float* __restrict__ ea, const int* __restrict__ eidx,
    const float* __restrict__ esh, const int* __restrict__ perm,
    const unsigned short* __restrict__ pw1, const unsigned short* __restrict__ pw2,
    const float* __restrict__ b1v, const float* __restrict__ b2v,
    const float* __restrict__ xnew, unsigned short* __restrict__ msg) {
  __shared__ __align__(16) unsigned short Hs[32 * 136];   // 128 + 8 pad
  __shared__ __align__(16) unsigned short EWs[32 * 392];  // 384 + 8 pad
  __shared__ float xgs[32 * 20];                          // 16 + 4 pad
  __shared__ float shs[32 * 4];

  const int t = threadIdx.x;
  const int b = blockIdx.y;
  const int e0 = blockIdx.x * 32;
  const int w = t >> 6, l = t & 63, q = l >> 4, lm = l & 15;

  // ---- phase 0: stage xg (double-indirect gather) and sh ----
  if (t < 128) {
    const int el = t >> 2, i0 = (t & 3) * 4;
    const int sid = perm[e0 + el];
    const int src = eidx[sid];
    const float4 v = *(const float4*)(xnew + ((size_t)b * N_CNT + src) * 16 + i0);
    xgs[el * 20 + i0 + 0] = v.x;
    xgs[el * 20 + i0 + 1] = v.y;
    xgs[el * 20 + i0 + 2] = v.z;
    xgs[el * 20 + i0 + 3] = v.w;
  } else if (t < 160) {
    const int el = t - 128;
    const int sid = perm[e0 + el];
    const float4 v = *(const float4*)(esh + ((size_t)b * E_CNT + sid) * 4);
    shs[el * 4 + 0] = v.x;
    shs[el * 4 + 1] = v.y;
    shs[el * 4 + 2] = v.z;
    shs[el * 4 + 3] = v.w;
  }

  // ---- GEMM1 ----
  f32x4 acc1[2][2];
#pragma unroll
  for (int mt = 0; mt < 2; ++mt)
#pragma unroll
    for (int j = 0; j < 2; ++j) acc1[mt][j] = (f32x4)0.0f;

  const float* eab = ea + (size_t)b * E_CNT * 128;
  const float* arow[2] = { eab + (size_t)perm[e0 + lm] * 128,
                           eab + (size_t)perm[e0 + 16 + lm] * 128 };
#pragma unroll
  for (int kk = 0; kk < 4; ++kk) {
    const s16x8 bf0 = *(const s16x8*)(pw1 + (((size_t)(2 * w + 0) * 4 + kk) * 64 + l) * 8);
    const s16x8 bf1 = *(const s16x8*)(pw1 + (((size_t)(2 * w + 1) * 4 + kk) * 64 + l) * 8);
#pragma unroll
    for (int mt = 0; mt < 2; ++mt) {
      const float* ap = arow[mt] + kk * 32 + q * 8;
      const float4 a0 = *(const float4*)ap;
      const float4 a1 = *(const float4*)(ap + 4);
      const s16x8 af = { f2bs(a0.x), f2bs(a0.y), f2bs(a0.z), f2bs(a0.w),
                         f2bs(a1.x), f2bs(a1.y), f2bs(a1.z), f2bs(a1.w) };
      acc1[mt][0] = __builtin_amdgcn_mfma_f32_16x16x32_bf16(af, bf0, acc1[mt][0], 0, 0, 0);
      acc1[mt][1] = __builtin_amdgcn_mfma_f32_16x16x32_bf16(af, bf1, acc1[mt][1], 0, 0, 0);
    }
  }
#pragma unroll
  for (int j = 0; j < 2; ++j) {
    const int n = (2 * w + j) * 16 + lm;
    const float bias = b1v[n];
#pragma unroll
    for (int mt = 0; mt < 2; ++mt)
#pragma unroll
      for (int r = 0; r < 4; ++r) {
        float v = acc1[mt][j][r] + bias;
        v = fmaxf(v, 0.0f);
        Hs[(mt * 16 + q * 4 + r) * 136 + n] = f2b(v);
      }
  }
  __syncthreads();

  // ---- GEMM2 ----
  f32x4 acc2[2][6];
#pragma unroll
  for (int mt = 0; mt < 2; ++mt)
#pragma unroll
    for (int jj = 0; jj < 6; ++jj) acc2[mt][jj] = (f32x4)0.0f;

#pragma unroll
  for (int kk = 0; kk < 4; ++kk) {
    s16x8 bw[6];
#pragma unroll
    for (int jj = 0; jj < 6; ++jj)
      bw[jj] = *(const s16x8*)(pw2 + (((size_t)(6 * w + jj) * 4 + kk) * 64 + l) * 8);
#pragma unroll
    for (int mt = 0; mt < 2; ++mt) {
      const s16x8 ah = *(const s16x8*)(&Hs[(mt * 16 + lm) * 136 + kk * 32 + q * 8]);
#pragma unroll
      for (int jj = 0; jj < 6; ++jj)
        acc2[mt][jj] = __builtin_amdgcn_mfma_f32_16x16x32_bf16(ah, bw[jj], acc2[mt][jj], 0, 0, 0);
    }
  }
#pragma unroll
  for (int jj = 0; jj < 6; ++jj) {
    const int n2 = (6 * w + jj) * 16 + lm;
    const float bias = b2v[n2];
#pragma unroll
    for (int mt = 0; mt < 2; ++mt)
#pragma unroll
      for (int r = 0; r < 4; ++r)
        EWs[(mt * 16 + q * 4 + r) * 392 + n2] = f2b(acc2[mt][jj][r] + bias);
  }
  __syncthreads();

  // ---- phase 3: messages, contiguous bf16 store (8 threads/edge, 5 ch each) ----
  {
    const int m = t >> 3;
    const int sub = t & 7;
    float xr[16];
#pragma unroll
    for (int i = 0; i < 16; ++i) xr[i] = xgs[m * 20 + i];
    const float sh0v = shs[m * 4 + 0];
    unsigned short* mp = msg + ((size_t)b * E_CNT + e0 + m) * 40;
    const int c0 = sub * 5;
    for (int cc = 0; cc < 5; ++cc) {
      const int c = c0 + cc;
      float accv = 0.0f, mul;
      if (c < 16) {
        const unsigned short* ep = &EWs[m * 392 + c];
#pragma unroll
        for (int i = 0; i < 16; ++i) accv += xr[i] * b2f(ep[i * 16]);
        mul = 0.25f * sh0v;  // ALPHA = 1/sqrt(16)
      } else {
        const int cr = c - 16;
        const int oo = cr / 3;
        const int md = cr - oo * 3;
        const unsigned short* ep = &EWs[m * 392 + 256 + oo];
#pragma unroll
        for (int i = 0; i < 16; ++i) accv += xr[i] * b2f(ep[i * 8]);
        mul = 0.25f * shs[m * 4 + 1 + md];
      }
      mp[c] = f2b(accv * mul);
    }
  }
}

// ---------------------------------------------------------------------------
// K_agg: CSR gather-aggregate. 24 (b,node) pairs per block; 240 active lanes
// as (sub 0..5, channel 0..39). Writes agg + per-block BN partials (no atomics).
// ---------------------------------------------------------------------------
__global__ __launch_bounds__(256) void k_agg(
    const unsigned short* __restrict__ msg, const int* __restrict__ rowptr,
    float* __restrict__ aggbuf, float* __restrict__ pbuf) {
  __shared__ float rs[240], rq[240];
  const int t = threadIdx.x;
  if (t < 240) {
    const int sub = t / 40, c = t - sub * 40;
    float bs = 0.f, bq = 0.f;
#pragma unroll
    for (int j = 0; j < 4; ++j) {
      const int p = blockIdx.x * AGG_PAIRS + j * 6 + sub;
      if (p < B_CNT * N_CNT) {
        const int b = p / N_CNT, n = p - b * N_CNT;
        const int r0 = rowptr[n], r1 = rowptr[n + 1];
        const int deg = r1 - r0;
        float acc = 0.f;
        const unsigned short* mp = msg + ((size_t)b * E_CNT + r0) * 40 + c;
        for (int k = 0; k < deg; ++k) acc += b2f(mp[(size_t)k * 40]);
        const float v = acc / fmaxf((float)deg, 1.f);
        aggbuf[(size_t)p * 40 + c] = v;
        bs += v; bq += v * v;
      }
    }
    rs[sub * 40 + c] = bs;
    rq[sub * 40 + c] = bq;
  }
  __syncthreads();
  if (t < 40) {
    float s0 = 0.f, q0 = 0.f;
#pragma unroll
    for (int j = 0; j < 6; ++j) { s0 += rs[j * 40 + t]; q0 += rq[j * 40 + t]; }
    pbuf[(size_t)blockIdx.x * 80 + t] = s0;
    pbuf[(size_t)blockIdx.x * 80 + 40 + t] = q0;
  }
}

// ---------------------------------------------------------------------------
// K_stats: reduce per-block BN partials, finalize scale/shift. One block.
// ---------------------------------------------------------------------------
__global__ void k_stats(const float* __restrict__ pbuf,
                        const float* __restrict__ gma, const float* __restrict__ bta,
                        float* __restrict__ scalev, float* __restrict__ shiftv) {
  __shared__ float red[240];
  const int t = threadIdx.x;
  if (t < 240) {
    const int seg = t / 80, col = t - seg * 80;
    const int j0 = seg * 556;
    const int j1 = (j0 + 556 < AGG_BLOCKS) ? (j0 + 556) : AGG_BLOCKS;
    float s = 0.f;
    for (int j = j0; j < j1; ++j) s += pbuf[(size_t)j * 80 + col];
    red[seg * 80 + col] = s;
  }
  __syncthreads();
  if (t < 40) {
    const float inv = 1.0f / (float)(B_CNT * N_CNT);
    const float su = red[t] + red[80 + t] + red[160 + t];
    const float sq = red[40 + t] + red[120 + t] + red[200 + t];
    const float mu = su * inv;
    const float var = fmaxf(sq * inv - mu * mu, 0.f);
    const float sc = rsqrtf(var + 1e-5f) * gma[t];
    scalev[t] = sc;
    shiftv[t] = bta[t] - mu * sc;
  }
}

// ---------------------------------------------------------------------------
// K_out: normalize + fp32 output.
// ---------------------------------------------------------------------------
__global__ void k_out(const float* __restrict__ agg, const float* __restrict__ scalev,
                      const float* __restrict__ shiftv, float* __restrict__ outp) {
  __shared__ float sc[40], sh[40];
  const int t = threadIdx.x;
  if (t < 40) { sc[t] = scalev[t]; sh[t] = shiftv[t]; }
  __syncthreads();
  const unsigned base = blockIdx.x * 1024u + t;
#pragma unroll
  for (int k2 = 0; k2 < 4; ++k2) {
    const unsigned idx = base + k2 * 256u;
    if (idx < 1600000u) {
      const unsigned row = idx / 40u;
      const unsigned ch = idx - row * 40u;
      outp[idx] = agg[idx] * sc[ch] + sh[ch];
    }
  }
}

// ---------------------------------------------------------------------------
// Workspace layout (bytes), total ~42.1 MB:
//   [0)            msg      32,000,000   (bf16, 4*100000*40)
//   [32,000,000)   aggbuf    6,400,000
//   [38,400,000)   xnew      2,560,000
//   [40,960,000)   pw1          32,768
//   [40,992,768)   pw2          98,304
//   [41,091,072)   rowptr       40,016   (10001 ints, padded)
//   [41,131,088)   cnt          40,000   (zeroed)
//   [41,171,088)   cursor       40,000   (zeroed; contiguous with cnt)
//   [41,211,088)   perm        400,000
//   [41,611,088)   pbuf        533,440   (1667 * 80 floats)
//   [42,144,528)   scalev          160
//   [42,144,688)   shiftv          160
// ---------------------------------------------------------------------------
extern "C" void kernel_launch(void* const* d_in, const int* in_sizes, int n_in,
                              void* d_out, int out_size, void* d_ws, size_t ws_size,
                              hipStream_t stream) {
  (void)in_sizes; (void)n_in; (void)out_size; (void)ws_size;
  const float* x    = (const float*)d_in[0];
  const int*   eidx = (const int*)d_in[1];
  const float* ea   = (const float*)d_in[2];
  const float* esh  = (const float*)d_in[3];
  const float* tcwr = (const float*)d_in[4];
  const float* tcwi = (const float*)d_in[5];
  const float* w1   = (const float*)d_in[6];
  const float* b1   = (const float*)d_in[7];
  const float* w2   = (const float*)d_in[8];
  const float* b2   = (const float*)d_in[9];
  const float* gma  = (const float*)d_in[10];
  const float* bta  = (const float*)d_in[11];

  char* ws = (char*)d_ws;
  unsigned short* msg    = (unsigned short*)(ws + 0);
  float*          aggbuf = (float*)(ws + 32000000);
  float*          xnew   = (float*)(ws + 38400000);
  unsigned short* pw1    = (unsigned short*)(ws + 40960000);
  unsigned short* pw2    = (unsigned short*)(ws + 40992768);
  int*            rowptr = (int*)(ws + 41091072);
  int*            cnt    = (int*)(ws + 41131088);
  int*            cursor = (int*)(ws + 41171088);
  int*            perm   = (int*)(ws + 41211088);
  float*          pbuf   = (float*)(ws + 41611088);
  float*          scalev = (float*)(ws + 42144528);
  float*          shiftv = (float*)(ws + 42144688);

  hipMemsetAsync(ws + 41131088, 0, 80000, stream);  // cnt + cursor
  k_pre<<<dim3(463), dim3(256), 0, stream>>>(x, tcwr, tcwi, w1, w2, eidx,
                                             xnew, pw1, pw2, cnt);
  k_scan<<<dim3(1), dim3(256), 0, stream>>>(cnt, rowptr);
  k_fill<<<dim3(391), dim3(256), 0, stream>>>(eidx, rowptr, cursor, perm);
  k_edge<<<dim3(E_CNT / 32, B_CNT), dim3(256), 0, stream>>>(
      ea, eidx, esh, perm, pw1, pw2, b1, b2, xnew, msg);
  k_agg<<<dim3(AGG_BLOCKS), dim3(256), 0, stream>>>(msg, rowptr, aggbuf, pbuf);
  k_stats<<<dim3(1), dim3(256), 0, stream>>>(pbuf, gma, bta, scalev, shiftv);
  k_out<<<dim3(1563), dim3(256), 0, stream>>>(aggbuf, scalev, shiftv, (float*)d_out);
}